// Round 3
// baseline (173.433 us; speedup 1.0000x reference)
//
#include <hip/hip_runtime.h>

#define BATCH 32
#define DIM 1024
#define NCH 302
#define KMIX 16
#define UNITS (NCH * KMIX * 3)   /* 14496 = 453 * 32 exactly */
#define NPOS 394
#define NTILE 32                 /* n-columns per block */
#define NSLICE 16                /* d-slices per block (512 threads) */
#define DSLICE (DIM / NSLICE)    /* 64 */

#if __has_builtin(__builtin_amdgcn_exp2f)
__device__ __forceinline__ float fast_exp_neghalf_sq(float t) {
  // exp(-0.5*t*t) = exp2(t*t * (-0.5*log2(e)))
  return __builtin_amdgcn_exp2f(t * t * (-0.72134752044448170f));
}
#else
__device__ __forceinline__ float fast_exp_neghalf_sq(float t) {
  return __expf(-0.5f * t * t);
}
#endif

// ---------------------------------------------------------------------------
// Kernel A: y[b][n] = sum_d x[b][d] * w[d][n] + bias[n]
// One block = 32 n-columns x full K=1024. 512 threads = 32 cols x 16
// d-slices of 64. Per-thread f32 accumulation (acc[32] over batch), w
// streamed with an 8-deep double-buffered prefetch (w is the HBM floor:
// 59.4 MB read exactly once — each block's 32-col tile is one aligned
// 128B segment per w row). x reads are half-wave-uniform float4 loads,
// L1/L2-resident (128 KB total). LDS tree-reduce, no atomics, no memset.
// ---------------------------------------------------------------------------
__global__ __launch_bounds__(512) void gemm_kernel(
    const float* __restrict__ x, const float* __restrict__ w,
    const float* __restrict__ bias, float* __restrict__ y)
{
  __shared__ float red[NSLICE][BATCH][NTILE];   // 64 KiB; 2-way bank alias = free
  const int tid   = threadIdx.x;
  const int col   = tid & 31;
  const int slice = tid >> 5;
  const int n0    = blockIdx.x * NTILE;
  const int dbase = slice * DSLICE;

  float acc[BATCH];
#pragma unroll
  for (int b = 0; b < BATCH; ++b) acc[b] = 0.0f;

  const float* wp = w + (size_t)dbase * UNITS + n0 + col;
  const float* xp = x + dbase;

  float wv[8], wn[8];
#pragma unroll
  for (int j = 0; j < 8; ++j) wv[j] = wp[(size_t)j * UNITS];

  for (int dd0 = 0; dd0 < DSLICE; dd0 += 8) {
    const int nxt = dd0 + 8;
    if (nxt < DSLICE) {
#pragma unroll
      for (int j = 0; j < 8; ++j) wn[j] = wp[(size_t)(nxt + j) * UNITS];
    }
#pragma unroll
    for (int b = 0; b < BATCH; ++b) {
      const float* xr = xp + b * DIM + dd0;
      const float4 x0 = *(const float4*)(xr);       // half-wave-uniform, cache hit
      const float4 x1 = *(const float4*)(xr + 4);
      acc[b] = fmaf(x0.x, wv[0], acc[b]);
      acc[b] = fmaf(x0.y, wv[1], acc[b]);
      acc[b] = fmaf(x0.z, wv[2], acc[b]);
      acc[b] = fmaf(x0.w, wv[3], acc[b]);
      acc[b] = fmaf(x1.x, wv[4], acc[b]);
      acc[b] = fmaf(x1.y, wv[5], acc[b]);
      acc[b] = fmaf(x1.z, wv[6], acc[b]);
      acc[b] = fmaf(x1.w, wv[7], acc[b]);
    }
#pragma unroll
    for (int j = 0; j < 8; ++j) wv[j] = wn[j];
  }

#pragma unroll
  for (int b = 0; b < BATCH; ++b) red[slice][b][col] = acc[b];
  __syncthreads();

  // 1024 outputs, 2 per thread: sum the 16 slice partials, add bias, store.
#pragma unroll
  for (int i = 0; i < 2; ++i) {
    const int oi = tid + i * 512;
    const int b  = oi >> 5;
    const int c  = oi & 31;
    float s = 0.0f;
#pragma unroll
    for (int sl = 0; sl < NSLICE; ++sl) s += red[sl][b][c];
    y[b * UNITS + n0 + c] = s + bias[n0 + c];
  }
}

// ---------------------------------------------------------------------------
// Kernel B: one wave per (b,c) pair. Uniform scalar loads of the 48 params,
// in-register softmax over 16 pi logits, lanes stride the 394 positions,
// 16 Gaussians per position. Floor: 61M v_exp_f32 ~ 3.1 us trans-bound.
// ---------------------------------------------------------------------------
__global__ __launch_bounds__(256) void mdn_kernel(
    const float* __restrict__ y, float* __restrict__ out)
{
  const int lane = threadIdx.x & 63;
  int pair = blockIdx.x * 4 + (threadIdx.x >> 6);
  pair = __builtin_amdgcn_readfirstlane(pair);   // uniform -> scalar param loads
  const int b = pair / NCH;
  const int c = pair - b * NCH;
  const float* yb = y + b * UNITS + c;

  // softmax over the 16 mixture logits (wave-uniform)
  float pi[KMIX];
  float m = -3.4e38f;
#pragma unroll
  for (int k = 0; k < KMIX; ++k) {
    pi[k] = yb[(2 * KMIX + k) * NCH];
    m = fmaxf(m, pi[k]);
  }
  float s = 0.0f;
#pragma unroll
  for (int k = 0; k < KMIX; ++k) { pi[k] = __expf(pi[k] - m); s += pi[k]; }
  const float inv_s = 1.0f / s;

  const float inv_sqrt_2pi = 0.39894228040143267f;
  float A[KMIX], B2[KMIX], C[KMIX];
#pragma unroll
  for (int k = 0; k < KMIX; ++k) {
    const float mu   = yb[k * NCH];
    const float sig  = yb[(KMIX + k) * NCH];
    const float isig = 1.0f / sig;
    A[k]  = isig;
    B2[k] = -mu * isig;
    C[k]  = pi[k] * inv_s * inv_sqrt_2pi * isig;
  }

  float* op = out + (size_t)pair * NPOS;
  for (int p = lane; p < NPOS; p += 64) {
    const float pos = (float)p * (1.0f / (NPOS - 1));
    float acc = 0.0f;
#pragma unroll
    for (int k = 0; k < KMIX; ++k) {
      const float t = fmaf(pos, A[k], B2[k]);
      acc = fmaf(C[k], fast_exp_neghalf_sq(t), acc);
    }
    op[p] = acc;
  }
}

extern "C" void kernel_launch(void* const* d_in, const int* in_sizes, int n_in,
                              void* d_out, int out_size, void* d_ws, size_t ws_size,
                              hipStream_t stream) {
  const float* x    = (const float*)d_in[0];
  const float* w    = (const float*)d_in[1];
  const float* bias = (const float*)d_in[2];
  float* out = (float*)d_out;
  float* y   = (float*)d_ws;                       // 32*14496 f32 = 1.86 MB

  gemm_kernel<<<UNITS / NTILE, 512, 0, stream>>>(x, w, bias, y);   // 453 blocks
  mdn_kernel<<<(BATCH * NCH) / 4, 256, 0, stream>>>(y, out);       // 2416 blocks
}

// Round 5
// 152.277 us; speedup vs baseline: 1.1389x; 1.1389x over previous
//
#include <hip/hip_runtime.h>

#define BATCH 32
#define DIM 1024
#define NCH 302
#define KMIX 16
#define UNITS 14496              /* NCH*KMIX*3 */
#define NPOS 394
#define KSPLIT 8
#define KCHUNK (DIM / KSPLIT)    /* 128 */
#define NTILE 256                /* n-cols per block (64 lanes x 4) */
#define NTILES ((UNITS + NTILE - 1) / NTILE)   /* 57 */
#define BSUB 8                   /* batches per wave */

// ---------------------------------------------------------------------------
// GEMM: grid (57 n-tiles, 8 k-chunks), 256 threads = 4 waves.
// Each wave owns 8 batches; each lane owns 4 n-cols (float4 w loads).
// x chunk (32b x 128d = 16KB) staged once in LDS, read as wave-uniform
// ds_read_b128 broadcasts. w read once from HBM (the floor), one 4-row
// group prefetched ahead. acc[8] float4 = 32 VGPR -> room to pipeline.
// K-partials stored to scratch (d_out), no atomics.
// ---------------------------------------------------------------------------
__global__ __launch_bounds__(256) void gemm_kernel(
    const float* __restrict__ x, const float* __restrict__ w,
    float* __restrict__ partial)
{
  __shared__ float xs[BATCH][KCHUNK];          // 16 KiB
  const int tid = threadIdx.x;
  const int k0  = blockIdx.y * KCHUNK;
  const int n0  = blockIdx.x * NTILE;

  // stage x[0:32][k0:k0+128]; 1024 float4s, 4 per thread, coalesced in d
#pragma unroll
  for (int j = 0; j < 4; ++j) {
    const int idx4 = tid + j * 256;
    const int b    = idx4 >> 5;                // 32 float4 per batch row
    const int d4   = idx4 & 31;
    const float4 v = *(const float4*)(x + b * DIM + k0 + d4 * 4);
    *(float4*)(&xs[b][d4 * 4]) = v;
  }
  __syncthreads();

  const int lane = tid & 63;
  const int bg   = tid >> 6;                   // wave id = batch group
  const bool st  = (n0 + lane * 4) < UNITS;    // tail-tile store mask
  int nc = n0 + lane * 4;
  if (nc > UNITS - 4) nc = UNITS - 4;          // clamp reads, mask stores

  float4 acc[BSUB];
#pragma unroll
  for (int bi = 0; bi < BSUB; ++bi) acc[bi] = make_float4(0.f, 0.f, 0.f, 0.f);

  const float* wp = w + (size_t)k0 * UNITS + nc;
  float4 wv[4], wn[4];
#pragma unroll
  for (int j = 0; j < 4; ++j) wv[j] = *(const float4*)(wp + (size_t)j * UNITS);

  for (int dd = 0; dd < KCHUNK; dd += 4) {
    if (dd + 4 < KCHUNK) {
#pragma unroll
      for (int j = 0; j < 4; ++j)
        wn[j] = *(const float4*)(wp + (size_t)(dd + 4 + j) * UNITS);
    }
#pragma unroll
    for (int bi = 0; bi < BSUB; ++bi) {
      const float4 xv = *(const float4*)(&xs[bg * BSUB + bi][dd]); // uniform bcast
      acc[bi].x = fmaf(xv.x, wv[0].x, acc[bi].x);
      acc[bi].y = fmaf(xv.x, wv[0].y, acc[bi].y);
      acc[bi].z = fmaf(xv.x, wv[0].z, acc[bi].z);
      acc[bi].w = fmaf(xv.x, wv[0].w, acc[bi].w);
      acc[bi].x = fmaf(xv.y, wv[1].x, acc[bi].x);
      acc[bi].y = fmaf(xv.y, wv[1].y, acc[bi].y);
      acc[bi].z = fmaf(xv.y, wv[1].z, acc[bi].z);
      acc[bi].w = fmaf(xv.y, wv[1].w, acc[bi].w);
      acc[bi].x = fmaf(xv.z, wv[2].x, acc[bi].x);
      acc[bi].y = fmaf(xv.z, wv[2].y, acc[bi].y);
      acc[bi].z = fmaf(xv.z, wv[2].z, acc[bi].z);
      acc[bi].w = fmaf(xv.z, wv[2].w, acc[bi].w);
      acc[bi].x = fmaf(xv.w, wv[3].x, acc[bi].x);
      acc[bi].y = fmaf(xv.w, wv[3].y, acc[bi].y);
      acc[bi].z = fmaf(xv.w, wv[3].z, acc[bi].z);
      acc[bi].w = fmaf(xv.w, wv[3].w, acc[bi].w);
    }
#pragma unroll
    for (int j = 0; j < 4; ++j) wv[j] = wn[j];
  }

  if (st) {
    float* pp = partial + ((size_t)blockIdx.y * BATCH + bg * BSUB) * UNITS + nc;
#pragma unroll
    for (int bi = 0; bi < BSUB; ++bi)
      *(float4*)(pp + (size_t)bi * UNITS) = acc[bi];
  }
}

// ---------------------------------------------------------------------------
// Reduce: y[b][n] = sum_k partial[k][b][n] + bias[n]. 453 blocks x 256 thr,
// one float4 per thread; partials are L2/L3-hot.
// ---------------------------------------------------------------------------
__global__ __launch_bounds__(256) void reduce_kernel(
    const float* __restrict__ partial, const float* __restrict__ bias,
    float* __restrict__ y)
{
  const int f4   = blockIdx.x * 256 + threadIdx.x;   // 0..115967
  const int base = f4 * 4;
  float4 s = make_float4(0.f, 0.f, 0.f, 0.f);
#pragma unroll
  for (int k = 0; k < KSPLIT; ++k) {
    const float4 v = *(const float4*)(partial + (size_t)k * (BATCH * UNITS) + base);
    s.x += v.x; s.y += v.y; s.z += v.z; s.w += v.w;
  }
  const int n = base % UNITS;                        // const-divisor -> magic mul
  const float4 bv = *(const float4*)(bias + n);
  s.x += bv.x; s.y += bv.y; s.z += bv.z; s.w += bv.w;
  *(float4*)(y + base) = s;
}

// ---------------------------------------------------------------------------
// MDN: one wave per (b,c). Softmax over 16 logits; k-outer loop with the
// wave's 7 positions held in registers -> 7 independent exps per k (trans
// ILP). Native exp2f: exp(-.5 t^2) = exp2(t^2 * -log2(e)/2).
// ---------------------------------------------------------------------------
__global__ __launch_bounds__(256) void mdn_kernel(
    const float* __restrict__ y, float* __restrict__ out)
{
  const int lane = threadIdx.x & 63;
  int pair = blockIdx.x * 4 + (threadIdx.x >> 6);
  pair = __builtin_amdgcn_readfirstlane(pair);
  const int b = pair / NCH;
  const int c = pair - b * NCH;
  const float* yb = y + b * UNITS + c;

  float pw[KMIX];
  float m = -3.4e38f;
#pragma unroll
  for (int k = 0; k < KMIX; ++k) {
    pw[k] = yb[(2 * KMIX + k) * NCH];
    m = fmaxf(m, pw[k]);
  }
  float ssum = 0.0f;
#pragma unroll
  for (int k = 0; k < KMIX; ++k) { pw[k] = __expf(pw[k] - m); ssum += pw[k]; }
  const float wnorm = 0.39894228040143267f / ssum;   // inv_sqrt_2pi / sum

  float posv[7];
#pragma unroll
  for (int i = 0; i < 7; ++i)
    posv[i] = (float)(lane + i * 64) * (1.0f / (NPOS - 1));

  float acc[7] = {0.f, 0.f, 0.f, 0.f, 0.f, 0.f, 0.f};
#pragma unroll
  for (int k = 0; k < KMIX; ++k) {
    const float mu   = yb[k * NCH];
    const float sig  = yb[(KMIX + k) * NCH];
    const float isig = 1.0f / sig;
    const float coef = pw[k] * wnorm * isig;
    const float nmu  = -mu * isig;
#pragma unroll
    for (int i = 0; i < 7; ++i) {
      const float t = fmaf(posv[i], isig, nmu);
      acc[i] = fmaf(coef, exp2f(t * t * -0.72134752044448170f), acc[i]);
    }
  }

  float* op = out + (size_t)pair * NPOS;
#pragma unroll
  for (int i = 0; i < 7; ++i) {
    const int p = lane + i * 64;
    if (p < NPOS) op[p] = acc[i];
  }
}

extern "C" void kernel_launch(void* const* d_in, const int* in_sizes, int n_in,
                              void* d_out, int out_size, void* d_ws, size_t ws_size,
                              hipStream_t stream) {
  const float* x    = (const float*)d_in[0];
  const float* w    = (const float*)d_in[1];
  const float* bias = (const float*)d_in[2];
  float* out     = (float*)d_out;
  float* partial = (float*)d_out;                  // 8*1.86MB = 14.85MB scratch,
                                                   // fully overwritten by mdn
  float* y       = (float*)d_ws;                   // 1.86 MB

  gemm_kernel<<<dim3(NTILES, KSPLIT), 256, 0, stream>>>(x, w, partial);
  reduce_kernel<<<(BATCH * UNITS / 4) / 256, 256, 0, stream>>>(partial, bias, y);
  mdn_kernel<<<(BATCH * NCH) / 4, 256, 0, stream>>>(y, out);
}

// Round 9
// 143.590 us; speedup vs baseline: 1.2078x; 1.0605x over previous
//
#include <hip/hip_runtime.h>

#define BATCH 32
#define DIM 1024
#define NCH 302
#define KMIX 16
#define UNITS 14496              /* NCH*KMIX*3 */
#define NPOS 394
#define KSPLIT 16
#define KCHUNK (DIM / KSPLIT)    /* 64 */
#define NTILE 256                /* n-cols per block */
#define NTILES 57                /* ceil(14496/256) */
#define BSUB 8                   /* batches per wave */
#define NPAIRS (BATCH * NCH)     /* 9664 */

// ---------------------------------------------------------------------------
// GEMM: grid (57 n-tiles x 16 k-chunks) = 912 blocks, 256 thr = 4 waves.
// Lane owns 4 n-cols (float4 w loads, depth-2 prefetch -> 8 float4 in
// flight/lane). x chunk (32x64 = 8KB) in LDS, wave-uniform broadcast reads.
// Partials -> d_ws. w (59.4MB) read exactly once = the HBM floor.
// ---------------------------------------------------------------------------
__global__ __launch_bounds__(256) void gemm_kernel(
    const float* __restrict__ x, const float* __restrict__ w,
    float* __restrict__ partial)
{
  __shared__ float xs[BATCH][KCHUNK];          // 8 KiB
  const int tid = threadIdx.x;
  const int kch = blockIdx.x / NTILES;
  const int tile = blockIdx.x - kch * NTILES;
  const int k0  = kch * KCHUNK;
  const int n0  = tile * NTILE;

  // stage x[0:32][k0:k0+64]: 512 float4s, 2 per thread
#pragma unroll
  for (int j = 0; j < 2; ++j) {
    const int idx4 = tid + j * 256;
    const int b    = idx4 >> 4;                // 16 float4 per batch row
    const int d4   = idx4 & 15;
    *(float4*)(&xs[b][d4 * 4]) = *(const float4*)(x + b * DIM + k0 + d4 * 4);
  }
  __syncthreads();

  const int lane = tid & 63;
  const int bg   = tid >> 6;
  const bool st  = (n0 + lane * 4) < UNITS;
  int nc = n0 + lane * 4;
  if (nc > UNITS - 4) nc = UNITS - 4;          // clamp reads, mask stores

  float4 acc[BSUB];
#pragma unroll
  for (int bi = 0; bi < BSUB; ++bi) acc[bi] = make_float4(0.f, 0.f, 0.f, 0.f);

  const float* wp = w + (size_t)k0 * UNITS + nc;
  float4 wa[4], wb[4];
#pragma unroll
  for (int j = 0; j < 4; ++j) wa[j] = *(const float4*)(wp + (size_t)j * UNITS);
#pragma unroll
  for (int j = 0; j < 4; ++j) wb[j] = *(const float4*)(wp + (size_t)(4 + j) * UNITS);

  for (int dd = 0; dd < KCHUNK; dd += 8) {
    const int nx = dd + 8;
    float4 wa2[4], wb2[4];
    if (nx < KCHUNK) {
#pragma unroll
      for (int j = 0; j < 4; ++j)
        wa2[j] = *(const float4*)(wp + (size_t)(nx + j) * UNITS);
    }
#pragma unroll
    for (int bi = 0; bi < BSUB; ++bi) {
      const float4 xv = *(const float4*)(&xs[bg * BSUB + bi][dd]);
      acc[bi].x = fmaf(xv.x, wa[0].x, acc[bi].x);
      acc[bi].y = fmaf(xv.x, wa[0].y, acc[bi].y);
      acc[bi].z = fmaf(xv.x, wa[0].z, acc[bi].z);
      acc[bi].w = fmaf(xv.x, wa[0].w, acc[bi].w);
      acc[bi].x = fmaf(xv.y, wa[1].x, acc[bi].x);
      acc[bi].y = fmaf(xv.y, wa[1].y, acc[bi].y);
      acc[bi].z = fmaf(xv.y, wa[1].z, acc[bi].z);
      acc[bi].w = fmaf(xv.y, wa[1].w, acc[bi].w);
      acc[bi].x = fmaf(xv.z, wa[2].x, acc[bi].x);
      acc[bi].y = fmaf(xv.z, wa[2].y, acc[bi].y);
      acc[bi].z = fmaf(xv.z, wa[2].z, acc[bi].z);
      acc[bi].w = fmaf(xv.z, wa[2].w, acc[bi].w);
      acc[bi].x = fmaf(xv.w, wa[3].x, acc[bi].x);
      acc[bi].y = fmaf(xv.w, wa[3].y, acc[bi].y);
      acc[bi].z = fmaf(xv.w, wa[3].z, acc[bi].z);
      acc[bi].w = fmaf(xv.w, wa[3].w, acc[bi].w);
    }
    if (nx < KCHUNK) {
#pragma unroll
      for (int j = 0; j < 4; ++j)
        wb2[j] = *(const float4*)(wp + (size_t)(nx + 4 + j) * UNITS);
    }
#pragma unroll
    for (int bi = 0; bi < BSUB; ++bi) {
      const float4 xv = *(const float4*)(&xs[bg * BSUB + bi][dd + 4]);
      acc[bi].x = fmaf(xv.x, wb[0].x, acc[bi].x);
      acc[bi].y = fmaf(xv.x, wb[0].y, acc[bi].y);
      acc[bi].z = fmaf(xv.x, wb[0].z, acc[bi].z);
      acc[bi].w = fmaf(xv.x, wb[0].w, acc[bi].w);
      acc[bi].x = fmaf(xv.y, wb[1].x, acc[bi].x);
      acc[bi].y = fmaf(xv.y, wb[1].y, acc[bi].y);
      acc[bi].z = fmaf(xv.y, wb[1].z, acc[bi].z);
      acc[bi].w = fmaf(xv.y, wb[1].w, acc[bi].w);
      acc[bi].x = fmaf(xv.z, wb[2].x, acc[bi].x);
      acc[bi].y = fmaf(xv.z, wb[2].y, acc[bi].y);
      acc[bi].z = fmaf(xv.z, wb[2].z, acc[bi].z);
      acc[bi].w = fmaf(xv.z, wb[2].w, acc[bi].w);
      acc[bi].x = fmaf(xv.w, wb[3].x, acc[bi].x);
      acc[bi].y = fmaf(xv.w, wb[3].y, acc[bi].y);
      acc[bi].z = fmaf(xv.w, wb[3].z, acc[bi].z);
      acc[bi].w = fmaf(xv.w, wb[3].w, acc[bi].w);
    }
    if (nx < KCHUNK) {
#pragma unroll
      for (int j = 0; j < 4; ++j) { wa[j] = wa2[j]; wb[j] = wb2[j]; }
    }
  }

  if (st) {
    float* pp = partial + ((size_t)kch * BATCH + bg * BSUB) * UNITS + nc;
#pragma unroll
    for (int bi = 0; bi < BSUB; ++bi)
      *(float4*)(pp + (size_t)bi * UNITS) = acc[bi];
  }
}

// ---------------------------------------------------------------------------
// Reduce + transpose: yt[(b*NCH + c)*48 + s] = sum_k partial[k][b][s*NCH+c]
// + bias[s*NCH+c], s = sec*16+kmix in [0,48). Coalesced float4 reads of the
// partials; scattered dword writes (fire-and-forget, 1.86MB).
// ---------------------------------------------------------------------------
__global__ __launch_bounds__(256) void reduce_kernel(
    const float* __restrict__ partial, const float* __restrict__ bias,
    float* __restrict__ yt)
{
  const int idx  = blockIdx.x * 256 + threadIdx.x;   // 0..115967
  const int base = idx * 4;                          // u-index into [b][n]
  float4 s4 = make_float4(0.f, 0.f, 0.f, 0.f);
#pragma unroll
  for (int k = 0; k < KSPLIT; ++k) {
    const float4 v = *(const float4*)(partial + (size_t)k * (BATCH * UNITS) + base);
    s4.x += v.x; s4.y += v.y; s4.z += v.z; s4.w += v.w;
  }
  const int b = base / UNITS;                        // const-divisor magic mul
  const int n = base - b * UNITS;
  const float4 bv = *(const float4*)(bias + n);
  s4.x += bv.x; s4.y += bv.y; s4.z += bv.z; s4.w += bv.w;

  float vs[4] = {s4.x, s4.y, s4.z, s4.w};
#pragma unroll
  for (int j = 0; j < 4; ++j) {
    const int nj = n + j;
    const int s  = nj / NCH;                         // magic mul
    const int c  = nj - s * NCH;
    yt[((size_t)b * NCH + c) * 48 + s] = vs[j];
  }
}

// ---------------------------------------------------------------------------
// MDN: block = 4 pairs (one per wave). Params for the 4 pairs are 768
// CONTIGUOUS bytes of yt -> one coalesced dword/thread stage into LDS,
// then wave-uniform broadcast reads. Pure compute after that: in-register
// softmax, k-outer with 7 register-resident positions (trans ILP).
// ---------------------------------------------------------------------------
__global__ __launch_bounds__(256) void mdn_kernel(
    const float* __restrict__ yt, float* __restrict__ out)
{
  __shared__ float ps[4][48];
  const int tid  = threadIdx.x;
  const int lane = tid & 63;
  const int bg   = tid >> 6;

  if (tid < 192) ps[tid / 48][tid % 48] = yt[(size_t)blockIdx.x * 192 + tid];
  __syncthreads();

  const int pair = blockIdx.x * 4 + bg;
  const float* pp = ps[bg];

  float pw[KMIX];
  float m = -3.4e38f;
#pragma unroll
  for (int k = 0; k < KMIX; ++k) {
    pw[k] = pp[32 + k];
    m = fmaxf(m, pw[k]);
  }
  float ssum = 0.0f;
#pragma unroll
  for (int k = 0; k < KMIX; ++k) { pw[k] = __expf(pw[k] - m); ssum += pw[k]; }
  const float wnorm = 0.39894228040143267f / ssum;   // inv_sqrt_2pi / sum

  float posv[7];
#pragma unroll
  for (int i = 0; i < 7; ++i)
    posv[i] = (float)(lane + i * 64) * (1.0f / (NPOS - 1));

  float acc[7] = {0.f, 0.f, 0.f, 0.f, 0.f, 0.f, 0.f};
#pragma unroll
  for (int k = 0; k < KMIX; ++k) {
    const float mu   = pp[k];
    const float sig  = pp[16 + k];
    const float isig = 1.0f / sig;
    const float coef = pw[k] * wnorm * isig;
    const float nmu  = -mu * isig;
#pragma unroll
    for (int i = 0; i < 7; ++i) {
      const float t = fmaf(posv[i], isig, nmu);
      acc[i] = fmaf(coef, exp2f(t * t * -0.72134752044448170f), acc[i]);
    }
  }

  float* op = out + (size_t)pair * NPOS;
#pragma unroll
  for (int i = 0; i < 7; ++i) {
    const int p = lane + i * 64;
    if (p < NPOS) op[p] = acc[i];
  }
}

extern "C" void kernel_launch(void* const* d_in, const int* in_sizes, int n_in,
                              void* d_out, int out_size, void* d_ws, size_t ws_size,
                              hipStream_t stream) {
  const float* x    = (const float*)d_in[0];
  const float* w    = (const float*)d_in[1];
  const float* bias = (const float*)d_in[2];
  float* out     = (float*)d_out;
  float* partial = (float*)d_ws;                                    // 29.7 MB
  float* yt      = (float*)((char*)d_ws + (size_t)32 * 1024 * 1024); // 1.86 MB

  gemm_kernel<<<NTILES * KSPLIT, 256, 0, stream>>>(x, w, partial);   // 912 blocks
  reduce_kernel<<<(BATCH * UNITS / 4) / 256, 256, 0, stream>>>(partial, bias, yt);
  mdn_kernel<<<NPAIRS / 4, 256, 0, stream>>>(yt, out);               // 2416 blocks
}

// Round 14
// 138.870 us; speedup vs baseline: 1.2489x; 1.0340x over previous
//
#include <hip/hip_runtime.h>

#define BATCH 32
#define DIM 1024
#define NCH 302
#define KMIX 16
#define UNITS 14496              /* NCH*KMIX*3 */
#define NPOS 394
#define KSPLIT 8
#define KCHUNK (DIM / KSPLIT)    /* 128 */
#define NTILE 256                /* n-cols per block */
#define NTILES 57                /* ceil(14496/256) */
#define BSUB 8                   /* batches per wave */
#define NPAIRS (BATCH * NCH)     /* 9664 */

// ---------------------------------------------------------------------------
// GEMM: grid (57 n-tiles x 8 k-chunks) = 456 blocks, 256 thr = 4 waves.
// Lane owns 4 n-cols (float4 w loads, depth-2 prefetch -> 8 float4 in
// flight/lane ~ 8KB/wave vs 2.3KB latency-BW product). x chunk (32x128 =
// 16KB) in LDS, wave-uniform broadcast reads. KSPLIT=8 keeps split-K
// traffic at 14.85MB each way (vs 29.7 at 16). w read exactly once.
// ---------------------------------------------------------------------------
__global__ __launch_bounds__(256) void gemm_kernel(
    const float* __restrict__ x, const float* __restrict__ w,
    float* __restrict__ partial)
{
  __shared__ float xs[BATCH][KCHUNK];          // 16 KiB
  const int tid = threadIdx.x;
  const int kch = blockIdx.x / NTILES;
  const int tile = blockIdx.x - kch * NTILES;
  const int k0  = kch * KCHUNK;
  const int n0  = tile * NTILE;

  // stage x[0:32][k0:k0+128]: 1024 float4s, 4 per thread, coalesced in d
#pragma unroll
  for (int j = 0; j < 4; ++j) {
    const int idx4 = tid + j * 256;
    const int b    = idx4 >> 5;                // 32 float4 per batch row
    const int d4   = idx4 & 31;
    *(float4*)(&xs[b][d4 * 4]) = *(const float4*)(x + b * DIM + k0 + d4 * 4);
  }
  __syncthreads();

  const int lane = tid & 63;
  const int bg   = tid >> 6;
  const bool st  = (n0 + lane * 4) < UNITS;
  int nc = n0 + lane * 4;
  if (nc > UNITS - 4) nc = UNITS - 4;          // clamp reads, mask stores

  float4 acc[BSUB];
#pragma unroll
  for (int bi = 0; bi < BSUB; ++bi) acc[bi] = make_float4(0.f, 0.f, 0.f, 0.f);

  const float* wp = w + (size_t)k0 * UNITS + nc;
  float4 wa[4], wb[4];
#pragma unroll
  for (int j = 0; j < 4; ++j) wa[j] = *(const float4*)(wp + (size_t)j * UNITS);
#pragma unroll
  for (int j = 0; j < 4; ++j) wb[j] = *(const float4*)(wp + (size_t)(4 + j) * UNITS);

  for (int dd = 0; dd < KCHUNK; dd += 8) {
    const int nx = dd + 8;
    float4 wa2[4], wb2[4];
    if (nx < KCHUNK) {
#pragma unroll
      for (int j = 0; j < 4; ++j)
        wa2[j] = *(const float4*)(wp + (size_t)(nx + j) * UNITS);
    }
#pragma unroll
    for (int bi = 0; bi < BSUB; ++bi) {
      const float4 xv = *(const float4*)(&xs[bg * BSUB + bi][dd]);
      acc[bi].x = fmaf(xv.x, wa[0].x, acc[bi].x);
      acc[bi].y = fmaf(xv.x, wa[0].y, acc[bi].y);
      acc[bi].z = fmaf(xv.x, wa[0].z, acc[bi].z);
      acc[bi].w = fmaf(xv.x, wa[0].w, acc[bi].w);
      acc[bi].x = fmaf(xv.y, wa[1].x, acc[bi].x);
      acc[bi].y = fmaf(xv.y, wa[1].y, acc[bi].y);
      acc[bi].z = fmaf(xv.y, wa[1].z, acc[bi].z);
      acc[bi].w = fmaf(xv.y, wa[1].w, acc[bi].w);
      acc[bi].x = fmaf(xv.z, wa[2].x, acc[bi].x);
      acc[bi].y = fmaf(xv.z, wa[2].y, acc[bi].y);
      acc[bi].z = fmaf(xv.z, wa[2].z, acc[bi].z);
      acc[bi].w = fmaf(xv.z, wa[2].w, acc[bi].w);
      acc[bi].x = fmaf(xv.w, wa[3].x, acc[bi].x);
      acc[bi].y = fmaf(xv.w, wa[3].y, acc[bi].y);
      acc[bi].z = fmaf(xv.w, wa[3].z, acc[bi].z);
      acc[bi].w = fmaf(xv.w, wa[3].w, acc[bi].w);
    }
    if (nx < KCHUNK) {
#pragma unroll
      for (int j = 0; j < 4; ++j)
        wb2[j] = *(const float4*)(wp + (size_t)(nx + 4 + j) * UNITS);
    }
#pragma unroll
    for (int bi = 0; bi < BSUB; ++bi) {
      const float4 xv = *(const float4*)(&xs[bg * BSUB + bi][dd + 4]);
      acc[bi].x = fmaf(xv.x, wb[0].x, acc[bi].x);
      acc[bi].y = fmaf(xv.x, wb[0].y, acc[bi].y);
      acc[bi].z = fmaf(xv.x, wb[0].z, acc[bi].z);
      acc[bi].w = fmaf(xv.x, wb[0].w, acc[bi].w);
      acc[bi].x = fmaf(xv.y, wb[1].x, acc[bi].x);
      acc[bi].y = fmaf(xv.y, wb[1].y, acc[bi].y);
      acc[bi].z = fmaf(xv.y, wb[1].z, acc[bi].z);
      acc[bi].w = fmaf(xv.y, wb[1].w, acc[bi].w);
      acc[bi].x = fmaf(xv.z, wb[2].x, acc[bi].x);
      acc[bi].y = fmaf(xv.z, wb[2].y, acc[bi].y);
      acc[bi].z = fmaf(xv.z, wb[2].z, acc[bi].z);
      acc[bi].w = fmaf(xv.z, wb[2].w, acc[bi].w);
      acc[bi].x = fmaf(xv.w, wb[3].x, acc[bi].x);
      acc[bi].y = fmaf(xv.w, wb[3].y, acc[bi].y);
      acc[bi].z = fmaf(xv.w, wb[3].z, acc[bi].z);
      acc[bi].w = fmaf(xv.w, wb[3].w, acc[bi].w);
    }
    if (nx < KCHUNK) {
#pragma unroll
      for (int j = 0; j < 4; ++j) { wa[j] = wa2[j]; wb[j] = wb2[j]; }
    }
  }

  if (st) {
    float* pp = partial + ((size_t)kch * BATCH + bg * BSUB) * UNITS + nc;
#pragma unroll
    for (int bi = 0; bi < BSUB; ++bi)
      *(float4*)(pp + (size_t)bi * UNITS) = acc[bi];
  }
}

// ---------------------------------------------------------------------------
// Fused reduce + MDN: block = 4 pairs (one per wave).
// Stage: thread t<192 owns (pair pi, param s): sums partial[k][b][s*NCH+c]
// over k=0..7 (each partial element read exactly once grid-wide; L3-hot,
// block's 4 consecutive c share lines) + bias -> ps[pi][s].
// Compute: in-register softmax + k-outer Gaussian eval with 7
// register-resident positions (trans-pipe ILP).
// ---------------------------------------------------------------------------
__global__ __launch_bounds__(256) void mdn_kernel(
    const float* __restrict__ partial, const float* __restrict__ bias,
    float* __restrict__ out)
{
  __shared__ float ps[4][48];
  const int tid  = threadIdx.x;
  const int lane = tid & 63;
  const int bg   = tid >> 6;
  const int p0   = blockIdx.x * 4;

  if (tid < 192) {
    const int pi = tid / 48;
    const int s  = tid - pi * 48;
    const int pr = p0 + pi;
    const int b  = pr / NCH;                   // const-divisor magic mul
    const int c  = pr - b * NCH;
    const int n  = s * NCH + c;
    float sum = bias[n];
#pragma unroll
    for (int k = 0; k < KSPLIT; ++k)
      sum += partial[((size_t)k * BATCH + b) * UNITS + n];
    ps[pi][s] = sum;
  }
  __syncthreads();

  const int pair = p0 + bg;
  const float* pp = ps[bg];

  float pw[KMIX];
  float m = -3.4e38f;
#pragma unroll
  for (int k = 0; k < KMIX; ++k) {
    pw[k] = pp[32 + k];
    m = fmaxf(m, pw[k]);
  }
  float ssum = 0.0f;
#pragma unroll
  for (int k = 0; k < KMIX; ++k) { pw[k] = __expf(pw[k] - m); ssum += pw[k]; }
  const float wnorm = 0.39894228040143267f / ssum;   // inv_sqrt_2pi / sum

  float posv[7];
#pragma unroll
  for (int i = 0; i < 7; ++i)
    posv[i] = (float)(lane + i * 64) * (1.0f / (NPOS - 1));

  float acc[7] = {0.f, 0.f, 0.f, 0.f, 0.f, 0.f, 0.f};
#pragma unroll
  for (int k = 0; k < KMIX; ++k) {
    const float mu   = pp[k];
    const float sig  = pp[16 + k];
    const float isig = 1.0f / sig;
    const float coef = pw[k] * wnorm * isig;
    const float nmu  = -mu * isig;
#pragma unroll
    for (int i = 0; i < 7; ++i) {
      const float t = fmaf(posv[i], isig, nmu);
      acc[i] = fmaf(coef, exp2f(t * t * -0.72134752044448170f), acc[i]);
    }
  }

  float* op = out + (size_t)pair * NPOS;
#pragma unroll
  for (int i = 0; i < 7; ++i) {
    const int p = lane + i * 64;
    if (p < NPOS) op[p] = acc[i];
  }
}

extern "C" void kernel_launch(void* const* d_in, const int* in_sizes, int n_in,
                              void* d_out, int out_size, void* d_ws, size_t ws_size,
                              hipStream_t stream) {
  const float* x    = (const float*)d_in[0];
  const float* w    = (const float*)d_in[1];
  const float* bias = (const float*)d_in[2];
  float* out     = (float*)d_out;
  float* partial = (float*)d_ws;                                    // 14.85 MB

  gemm_kernel<<<NTILES * KSPLIT, 256, 0, stream>>>(x, w, partial);   // 456 blocks
  mdn_kernel<<<NPAIRS / 4, 256, 0, stream>>>(partial, bias, out);    // 2416 blocks
}